// Round 4
// baseline (665.975 us; speedup 1.0000x reference)
//
#include <hip/hip_runtime.h>

#define N_NODES 50000
#define N_EDGES 800000
#define F1 64
#define F2 16
#define NBINS 196      // ceil(50000/256)
#define BIN_SHIFT 8    // 256 nodes per bin
#define EPB 4096       // edges per binscatter block
#define NSB ((N_EDGES + EPB - 1) / EPB)  // 196

// ---------------- degree ----------------
__global__ void k_zero(int* __restrict__ cnt) {
    int i = blockIdx.x * blockDim.x + threadIdx.x;
    if (i < N_NODES) cnt[i] = 0;
}

__global__ void k_count(const int* __restrict__ dst, int* __restrict__ cnt) {
    int i = blockIdx.x * blockDim.x + threadIdx.x;
    if (i < N_EDGES) atomicAdd(&cnt[dst[i]], 1);
}

__global__ void k_dinv(const int* __restrict__ cnt, float* __restrict__ dinv) {
    int i = blockIdx.x * blockDim.x + threadIdx.x;
    if (i < N_NODES) dinv[i] = rsqrtf(1.0f + (float)cnt[i]);  // +1 self-loop
}

// ---------------- bin offsets: per-bin edge counts from node counts + scan ----------------
__global__ void k_binoff(const int* __restrict__ cnt, int* __restrict__ bin_start,
                         int* __restrict__ cursor) {
    __shared__ int bs[256];
    int t = threadIdx.x;           // 256 = 4 waves
    int lane = t & 63, wid = t >> 6;
    bs[t] = 0;
    __syncthreads();
    for (int b = wid; b < NBINS; b += 4) {      // wave per bin
        int sum = 0;
#pragma unroll
        for (int i = 0; i < 4; ++i) {
            int idx = (b << BIN_SHIFT) + i * 64 + lane;
            if (idx < N_NODES) sum += cnt[idx];
        }
        for (int s = 1; s < 64; s <<= 1) sum += __shfl_xor(sum, s);
        if (lane == 0) bs[b] = sum;
    }
    __syncthreads();
    int v = bs[t];
    for (int s = 1; s < 256; s <<= 1) {          // Hillis-Steele inclusive
        int u = (t >= s) ? bs[t - s] : 0;
        __syncthreads();
        bs[t] += u;
        __syncthreads();
    }
    int excl = bs[t] - v;                        // exclusive
    if (t <= NBINS) bin_start[t] = excl;         // bin_start[NBINS] = total = N_EDGES
    if (t < NBINS) cursor[t] = excl;
}

// ---------------- coarse-bin the edges: pairs[] grouped by (dst>>8) ----------------
__global__ void k_binscatter(const int* __restrict__ src, const int* __restrict__ dst,
                             int* __restrict__ cursor, unsigned* __restrict__ pairs) {
    __shared__ int hist[NBINS];
    __shared__ int loff[NBINS];
    __shared__ int lcur[NBINS];
    __shared__ int gbase[NBINS];
    __shared__ int scanbuf[256];
    __shared__ unsigned stage[EPB];
    int t = threadIdx.x;                         // 256
    int e0 = blockIdx.x * EPB;
    int eend = min(e0 + EPB, N_EDGES);

    for (int i = t; i < NBINS; i += 256) hist[i] = 0;
    __syncthreads();
    for (int e = e0 + t; e < eend; e += 256)
        atomicAdd(&hist[dst[e] >> BIN_SHIFT], 1);
    __syncthreads();
    // scan the 196-bin histogram -> local offsets
    int v = (t < NBINS) ? hist[t] : 0;
    scanbuf[t] = v;
    __syncthreads();
    for (int s = 1; s < 256; s <<= 1) {
        int u = (t >= s) ? scanbuf[t - s] : 0;
        __syncthreads();
        scanbuf[t] += u;
        __syncthreads();
    }
    if (t < NBINS) { loff[t] = scanbuf[t] - v; lcur[t] = scanbuf[t] - v; }
    __syncthreads();
    // stage packed edges in LDS, bin-contiguous
    for (int e = e0 + t; e < eend; e += 256) {
        int d = dst[e];
        int b = d >> BIN_SHIFT;
        int pos = atomicAdd(&lcur[b], 1);
        stage[pos] = (unsigned)src[e] | ((unsigned)(d & 255) << 16);  // src<2^16
    }
    __syncthreads();
    // reserve global runs (one atomic per (block,bin))
    if (t < NBINS) gbase[t] = atomicAdd(&cursor[t], hist[t]);
    __syncthreads();
    // lane-cooperative contiguous flush -> full-line writes
    int lane = t & 63, wid = t >> 6;
    for (int b = wid; b < NBINS; b += 4) {
        int n = hist[b], lb = loff[b], gb = gbase[b];
        for (int i = lane; i < n; i += 64) pairs[gb + i] = stage[lb + i];
    }
}

// ---------------- layer 1 GEMM: h0 = x @ W1 ----------------
__global__ void k_gemm1(const float* __restrict__ x, const float* __restrict__ W1,
                        float* __restrict__ h0) {
    __shared__ float Ws[F1 * F1];
    __shared__ float Xs[4 * F1];
    int tid = threadIdx.x;          // 256, one wave per row
    int row_local = tid >> 6;
    int col = tid & 63;
    int row = blockIdx.x * 4 + row_local;

    for (int i = tid; i < F1 * F1; i += 256) Ws[i] = W1[i];
    Xs[tid] = x[blockIdx.x * 4 * F1 + tid];
    __syncthreads();

    const float* xr = &Xs[row_local * F1];
    float acc = 0.f;
#pragma unroll
    for (int k = 0; k < F1; ++k) acc += xr[k] * Ws[k * F1 + col];
    h0[row * F1 + col] = acc;
}

// ---------------- layer 1 binned gather: LDS accumulator, edge-parallel ----------------
__global__ void __launch_bounds__(1024) k_gather1_bin(
        const int* __restrict__ bin_start, const unsigned* __restrict__ pairs,
        const float* __restrict__ dinv, const float* __restrict__ h0,
        float* __restrict__ agg1) {
    __shared__ float acc[256 * F1];  // 64 KB
    int t = threadIdx.x, lane = t & 63, wid = t >> 6;  // 16 waves
    int b = blockIdx.x;
    for (int i = t; i < 256 * F1; i += 1024) acc[i] = 0.f;
    __syncthreads();

    int start = bin_start[b], end = bin_start[b + 1];
    int e = start + wid;                 // one edge per wave per slot, stride 16
    for (; e + 48 < end; e += 64) {      // 4 independent chains for latency hiding
        unsigned p0 = pairs[e], p1 = pairs[e + 16], p2 = pairs[e + 32], p3 = pairs[e + 48];
        int s0 = p0 & 0xFFFF, s1 = p1 & 0xFFFF, s2 = p2 & 0xFFFF, s3 = p3 & 0xFFFF;
        float w0 = dinv[s0], w1 = dinv[s1], w2 = dinv[s2], w3 = dinv[s3];
        float v0 = h0[s0 * F1 + lane], v1 = h0[s1 * F1 + lane];
        float v2 = h0[s2 * F1 + lane], v3 = h0[s3 * F1 + lane];
        atomicAdd(&acc[((p0 >> 16) << 6) + lane], w0 * v0);
        atomicAdd(&acc[((p1 >> 16) << 6) + lane], w1 * v1);
        atomicAdd(&acc[((p2 >> 16) << 6) + lane], w2 * v2);
        atomicAdd(&acc[((p3 >> 16) << 6) + lane], w3 * v3);
    }
    for (; e < end; e += 16) {
        unsigned p = pairs[e];
        int s = p & 0xFFFF;
        atomicAdd(&acc[((p >> 16) << 6) + lane], dinv[s] * h0[s * F1 + lane]);
    }
    __syncthreads();

    int nb = min(256, N_NODES - (b << BIN_SHIFT));
    for (int r = wid; r < nb; r += 16) {
        int d = (b << BIN_SHIFT) + r;
        float dd = dinv[d];
        agg1[d * F1 + lane] = dd * (acc[(r << 6) + lane] + dd * h0[d * F1 + lane]);
    }
}

// ---------------- layer 2 GEMM: h1 = relu(agg1 + b1) @ W2 ----------------
__global__ void k_gemm2(const float* __restrict__ agg1, const float* __restrict__ b1,
                        const float* __restrict__ W2, float* __restrict__ h1) {
    __shared__ float Ws[F1 * F2];
    __shared__ float As[16 * 65];
    int tid = threadIdx.x;              // 256
    int rl = tid >> 4;
    int col = tid & 15;
    int row = blockIdx.x * 16 + rl;

    for (int i = tid; i < F1 * F2; i += 256) Ws[i] = W2[i];
    for (int i = tid; i < 16 * F1; i += 256) {
        int k = i & 63;
        float v = agg1[blockIdx.x * 16 * F1 + i] + b1[k];
        As[(i >> 6) * 65 + k] = v > 0.f ? v : 0.f;
    }
    __syncthreads();

    const float* ar = &As[rl * 65];
    float acc = 0.f;
#pragma unroll
    for (int k = 0; k < F1; ++k) acc += ar[k] * Ws[k * F2 + col];
    h1[row * F2 + col] = acc;
}

// ---------------- layer 2 binned gather ----------------
__global__ void __launch_bounds__(1024) k_gather2_bin(
        const int* __restrict__ bin_start, const unsigned* __restrict__ pairs,
        const float* __restrict__ dinv, const float* __restrict__ h1,
        const float* __restrict__ b2, float* __restrict__ out) {
    __shared__ float acc[256 * F2];  // 16 KB
    int t = threadIdx.x, lane = t & 63, wid = t >> 6;  // 16 waves
    int j = lane >> 4, f = lane & 15;                   // 4 edges per wave slot
    int b = blockIdx.x;
    for (int i = t; i < 256 * F2; i += 1024) acc[i] = 0.f;
    __syncthreads();

    int start = bin_start[b], end = bin_start[b + 1];
    int e = start + (wid << 2) + j;      // stride 64 across block
    for (; e + 64 < end; e += 128) {     // 2 chains
        unsigned p0 = pairs[e], p1 = pairs[e + 64];
        int s0 = p0 & 0xFFFF, s1 = p1 & 0xFFFF;
        float v0 = dinv[s0] * h1[s0 * F2 + f];
        float v1 = dinv[s1] * h1[s1 * F2 + f];
        atomicAdd(&acc[(p0 >> 16) * F2 + f], v0);
        atomicAdd(&acc[(p1 >> 16) * F2 + f], v1);
    }
    for (; e < end; e += 64) {
        unsigned p = pairs[e];
        int s = p & 0xFFFF;
        atomicAdd(&acc[(p >> 16) * F2 + f], dinv[s] * h1[s * F2 + f]);
    }
    __syncthreads();

    int nb = min(256, N_NODES - (b << BIN_SHIFT));
    for (int r = (wid << 2) + j; r < nb; r += 64) {
        int d = (b << BIN_SHIFT) + r;
        float dd = dinv[d];
        out[d * F2 + f] = b2[f] + dd * (acc[r * F2 + f] + dd * h1[d * F2 + f]);
    }
}

extern "C" void kernel_launch(void* const* d_in, const int* in_sizes, int n_in,
                              void* d_out, int out_size, void* d_ws, size_t ws_size,
                              hipStream_t stream) {
    const float* x  = (const float*)d_in[0];          // [50000, 64]
    const int*   ei = (const int*)d_in[1];            // [2, 800000]
    const float* W1 = (const float*)d_in[2];          // [64, 64]
    const float* b1 = (const float*)d_in[3];          // [64]
    const float* W2 = (const float*)d_in[4];          // [64, 16]
    const float* b2 = (const float*)d_in[5];          // [16]
    float* out = (float*)d_out;                       // [50000, 16]

    const int* src = ei;
    const int* dst = ei + N_EDGES;

    // ws layout (4B words), lifetime-overlapped, total 29.0 MB:
    //   dinv      [0, 50048)
    //   bin_start [50048, 50304)          (197 used)
    //   pairs     [50304, 850304)         ; nodecnt aliases pairs[0:50000] (dead before binscatter)
    //   h0 / h1   [850304, 4050304)
    //   agg1      [4050304, 7250304)      ; cursor aliases agg1[0:196] (dead before gather1)
    float*    dinv      = (float*)d_ws;
    int*      bin_start = (int*)d_ws + 50048;
    unsigned* pairs     = (unsigned*)d_ws + 50304;
    float*    h0        = (float*)d_ws + 850304;
    float*    agg1      = (float*)d_ws + 4050304;
    int*      nodecnt   = (int*)pairs;       // dead once k_binoff ran; binscatter then overwrites
    int*      cursor    = (int*)agg1;        // dead once k_binscatter ran; gather1 then overwrites
    float*    h1        = h0;                // h0 dead after gather1

    k_zero      <<<(N_NODES + 255) / 256, 256, 0, stream>>>(nodecnt);
    k_count     <<<(N_EDGES + 255) / 256, 256, 0, stream>>>(dst, nodecnt);
    k_dinv      <<<(N_NODES + 255) / 256, 256, 0, stream>>>(nodecnt, dinv);
    k_binoff    <<<1, 256, 0, stream>>>(nodecnt, bin_start, cursor);
    k_binscatter<<<NSB, 256, 0, stream>>>(src, dst, cursor, pairs);

    k_gemm1      <<<N_NODES / 4, 256, 0, stream>>>(x, W1, h0);
    k_gather1_bin<<<NBINS, 1024, 0, stream>>>(bin_start, pairs, dinv, h0, agg1);
    k_gemm2      <<<N_NODES / 16, 256, 0, stream>>>(agg1, b1, W2, h1);
    k_gather2_bin<<<NBINS, 1024, 0, stream>>>(bin_start, pairs, dinv, h1, b2, out);
}

// Round 5
// 236.158 us; speedup vs baseline: 2.8200x; 2.8200x over previous
//
#include <hip/hip_runtime.h>

#define N_NODES 50000
#define N_EDGES 800000
#define F1 64
#define F2 16
#define NBINS 196      // ceil(50000/256)
#define BIN_SHIFT 8    // 256 nodes per bin
#define EPB 4096       // edges per binscatter block
#define NSB ((N_EDGES + EPB - 1) / EPB)   // 196
#define SCAN_NB 196    // ceil(50000/256)
#define STAGE_MAX 6144 // max edges per bin (mean 4096, sigma ~64 -> +32 sigma)

// ---------------- degree ----------------
__global__ void k_zero(int* __restrict__ cnt) {
    int i = blockIdx.x * blockDim.x + threadIdx.x;
    if (i < N_NODES) cnt[i] = 0;
}

__global__ void k_count(const int* __restrict__ dst, int* __restrict__ cnt) {
    int i = blockIdx.x * blockDim.x + threadIdx.x;
    if (i < N_EDGES) atomicAdd(&cnt[dst[i]], 1);
}

__global__ void k_dinv(const int* __restrict__ cnt, float* __restrict__ dinv) {
    int i = blockIdx.x * blockDim.x + threadIdx.x;
    if (i < N_NODES) dinv[i] = rsqrtf(1.0f + (float)cnt[i]);  // +1 self-loop
}

// ---------------- hierarchical exclusive scan: cnt -> node_start ----------------
__global__ void k_scan_local(const int* __restrict__ cnt, int* __restrict__ node_start,
                             int* __restrict__ bsum) {
    __shared__ int tmp[256];
    int t = threadIdx.x;
    int g = blockIdx.x * 256 + t;
    int v = (g < N_NODES) ? cnt[g] : 0;
    tmp[t] = v;
    __syncthreads();
    for (int s = 1; s < 256; s <<= 1) {
        int u = (t >= s) ? tmp[t - s] : 0;
        __syncthreads();
        tmp[t] += u;
        __syncthreads();
    }
    if (g < N_NODES) node_start[g] = tmp[t] - v;  // exclusive
    if (t == 255) bsum[blockIdx.x] = tmp[255];
}

__global__ void k_scan_sums(int* __restrict__ bsum) {
    __shared__ int tmp[256];
    int t = threadIdx.x;
    int v = (t < SCAN_NB) ? bsum[t] : 0;
    tmp[t] = v;
    __syncthreads();
    for (int s = 1; s < 256; s <<= 1) {
        int u = (t >= s) ? tmp[t - s] : 0;
        __syncthreads();
        tmp[t] += u;
        __syncthreads();
    }
    if (t < SCAN_NB) bsum[t] = tmp[t] - v;
}

// add block prefix; init per-bin cursors; cap node_start
__global__ void k_scan_add(int* __restrict__ node_start, const int* __restrict__ bsum,
                           int* __restrict__ cursor) {
    int g = blockIdx.x * 256 + threadIdx.x;
    if (g < N_NODES) {
        int v = node_start[g] + bsum[blockIdx.x];
        node_start[g] = v;
        if ((g & 255) == 0) cursor[g >> BIN_SHIFT] = v;  // bin base = node_start[b<<8]
    }
    if (g == 0) node_start[N_NODES] = N_EDGES;
}

// ---------------- pass 1: coarse-bin edges by dst>>8 (coalesced writes) ----------------
__global__ void k_binscatter(const int* __restrict__ src, const int* __restrict__ dst,
                             int* __restrict__ cursor, unsigned* __restrict__ pairs) {
    __shared__ int hist[NBINS];
    __shared__ int loff[NBINS];
    __shared__ int lcur[NBINS];
    __shared__ int gbase[NBINS];
    __shared__ int scanbuf[256];
    __shared__ unsigned stage[EPB];
    int t = threadIdx.x;                         // 256
    int e0 = blockIdx.x * EPB;
    int eend = min(e0 + EPB, N_EDGES);

    for (int i = t; i < NBINS; i += 256) hist[i] = 0;
    __syncthreads();
    for (int e = e0 + t; e < eend; e += 256)
        atomicAdd(&hist[dst[e] >> BIN_SHIFT], 1);
    __syncthreads();
    int v = (t < NBINS) ? hist[t] : 0;
    scanbuf[t] = v;
    __syncthreads();
    for (int s = 1; s < 256; s <<= 1) {
        int u = (t >= s) ? scanbuf[t - s] : 0;
        __syncthreads();
        scanbuf[t] += u;
        __syncthreads();
    }
    if (t < NBINS) { loff[t] = scanbuf[t] - v; lcur[t] = scanbuf[t] - v; }
    __syncthreads();
    for (int e = e0 + t; e < eend; e += 256) {
        int d = dst[e];
        int b = d >> BIN_SHIFT;
        int pos = atomicAdd(&lcur[b], 1);
        stage[pos] = (unsigned)src[e] | ((unsigned)(d & 255) << 16);  // src < 2^16
    }
    __syncthreads();
    if (t < NBINS) gbase[t] = atomicAdd(&cursor[t], hist[t]);
    __syncthreads();
    int lane = t & 63, wid = t >> 6;
    for (int b = wid; b < NBINS; b += 4) {
        int n = hist[b], lb = loff[b], gb = gbase[b];
        for (int i = lane; i < n; i += 64) pairs[gb + i] = stage[lb + i];
    }
}

// ---------------- pass 2: per-bin counting sort -> node-sorted ushort CSR ----------------
__global__ void k_binsort(const int* __restrict__ node_start, const unsigned* __restrict__ pairs,
                          unsigned short* __restrict__ csr) {
    __shared__ int hist[256];
    __shared__ int lcur[256];
    __shared__ int scanbuf[256];
    __shared__ unsigned short stage[STAGE_MAX];
    int t = threadIdx.x;                         // 256
    int b = blockIdx.x;
    int lo = b << BIN_SHIFT;
    int hi = min(lo + 256, N_NODES);
    int start = node_start[lo], end = node_start[hi];
    int n = end - start;

    hist[t] = 0;
    __syncthreads();
    for (int i = t; i < n; i += 256)
        atomicAdd(&hist[pairs[start + i] >> 16], 1);
    __syncthreads();
    int v = hist[t];
    scanbuf[t] = v;
    __syncthreads();
    for (int s = 1; s < 256; s <<= 1) {
        int u = (t >= s) ? scanbuf[t - s] : 0;
        __syncthreads();
        scanbuf[t] += u;
        __syncthreads();
    }
    lcur[t] = scanbuf[t] - v;                    // exclusive
    __syncthreads();
    for (int i = t; i < n; i += 256) {
        unsigned p = pairs[start + i];
        int pos = atomicAdd(&lcur[p >> 16], 1);
        stage[pos] = (unsigned short)(p & 0xFFFF);
    }
    __syncthreads();
    for (int i = t; i < n; i += 256) csr[start + i] = stage[i];  // coalesced
}

// ---------------- layer 1 GEMM: h0 = x @ W1 ----------------
__global__ void k_gemm1(const float* __restrict__ x, const float* __restrict__ W1,
                        float* __restrict__ h0) {
    __shared__ float Ws[F1 * F1];
    __shared__ float Xs[4 * F1];
    int tid = threadIdx.x;          // 256, one wave per row
    int row_local = tid >> 6;
    int col = tid & 63;
    int row = blockIdx.x * 4 + row_local;

    for (int i = tid; i < F1 * F1; i += 256) Ws[i] = W1[i];
    Xs[tid] = x[blockIdx.x * 4 * F1 + tid];
    __syncthreads();

    const float* xr = &Xs[row_local * F1];
    float acc = 0.f;
#pragma unroll
    for (int k = 0; k < F1; ++k) acc += xr[k] * Ws[k * F1 + col];
    h0[row * F1 + col] = acc;
}

// ---------------- layer 1 pull gather (float4, 4 edges/wave/iter) ----------------
__global__ void k_gather1(const int* __restrict__ node_start, const unsigned short* __restrict__ csr,
                          const float* __restrict__ dinv, const float4* __restrict__ h04,
                          float4* __restrict__ agg14) {
    int t = threadIdx.x;                 // 256 = 4 waves, one node per wave
    int lane = t & 63;
    int j = lane >> 4, f = lane & 15;    // 4 edge-groups x 16B feature slice
    int d = blockIdx.x * 4 + (t >> 6);
    int start = node_start[d], end = node_start[d + 1];
    float4 acc = {0.f, 0.f, 0.f, 0.f};
    int i = start + j;
    for (; i + 4 < end; i += 8) {        // 2 chains for MLP
        int s0 = csr[i], s1 = csr[i + 4];
        float w0 = dinv[s0], w1 = dinv[s1];
        float4 v0 = h04[s0 * 16 + f], v1 = h04[s1 * 16 + f];
        acc.x += w0 * v0.x + w1 * v1.x;
        acc.y += w0 * v0.y + w1 * v1.y;
        acc.z += w0 * v0.z + w1 * v1.z;
        acc.w += w0 * v0.w + w1 * v1.w;
    }
    if (i < end) {
        int s = csr[i];
        float w = dinv[s];
        float4 v = h04[s * 16 + f];
        acc.x += w * v.x; acc.y += w * v.y; acc.z += w * v.z; acc.w += w * v.w;
    }
#pragma unroll
    for (int m = 16; m <= 32; m <<= 1) {
        acc.x += __shfl_xor(acc.x, m);
        acc.y += __shfl_xor(acc.y, m);
        acc.z += __shfl_xor(acc.z, m);
        acc.w += __shfl_xor(acc.w, m);
    }
    if (j == 0) {
        float dd = dinv[d];
        float4 sv = h04[d * 16 + f];
        float4 r;
        r.x = dd * (acc.x + dd * sv.x);
        r.y = dd * (acc.y + dd * sv.y);
        r.z = dd * (acc.z + dd * sv.z);
        r.w = dd * (acc.w + dd * sv.w);
        agg14[d * 16 + f] = r;
    }
}

// ---------------- layer 2 GEMM: h1 = relu(agg1 + b1) @ W2 ----------------
__global__ void k_gemm2(const float* __restrict__ agg1, const float* __restrict__ b1,
                        const float* __restrict__ W2, float* __restrict__ h1) {
    __shared__ float Ws[F1 * F2];
    __shared__ float As[16 * 65];
    int tid = threadIdx.x;              // 256
    int rl = tid >> 4;
    int col = tid & 15;
    int row = blockIdx.x * 16 + rl;

    for (int i = tid; i < F1 * F2; i += 256) Ws[i] = W2[i];
    for (int i = tid; i < 16 * F1; i += 256) {
        int k = i & 63;
        float v = agg1[blockIdx.x * 16 * F1 + i] + b1[k];
        As[(i >> 6) * 65 + k] = v > 0.f ? v : 0.f;
    }
    __syncthreads();

    const float* ar = &As[rl * 65];
    float acc = 0.f;
#pragma unroll
    for (int k = 0; k < F1; ++k) acc += ar[k] * Ws[k * F2 + col];
    h1[row * F2 + col] = acc;
}

// ---------------- layer 2 pull gather (float4, 16 edges/wave/iter) ----------------
__global__ void k_gather2(const int* __restrict__ node_start, const unsigned short* __restrict__ csr,
                          const float* __restrict__ dinv, const float4* __restrict__ h14,
                          const float4* __restrict__ b24, float4* __restrict__ out4) {
    int t = threadIdx.x;                 // 256 = 4 waves, one node per wave
    int lane = t & 63;
    int j = lane >> 2, f = lane & 3;     // 16 edge-groups x 16B slice (F2=16)
    int d = blockIdx.x * 4 + (t >> 6);
    int start = node_start[d], end = node_start[d + 1];
    float4 acc = {0.f, 0.f, 0.f, 0.f};
    for (int i = start + j; i < end; i += 16) {
        int s = csr[i];
        float w = dinv[s];
        float4 v = h14[s * 4 + f];
        acc.x += w * v.x; acc.y += w * v.y; acc.z += w * v.z; acc.w += w * v.w;
    }
#pragma unroll
    for (int m = 4; m <= 32; m <<= 1) {
        acc.x += __shfl_xor(acc.x, m);
        acc.y += __shfl_xor(acc.y, m);
        acc.z += __shfl_xor(acc.z, m);
        acc.w += __shfl_xor(acc.w, m);
    }
    if (j == 0) {
        float dd = dinv[d];
        float4 sv = h14[d * 4 + f];
        float4 bb = b24[f];
        float4 r;
        r.x = bb.x + dd * (acc.x + dd * sv.x);
        r.y = bb.y + dd * (acc.y + dd * sv.y);
        r.z = bb.z + dd * (acc.z + dd * sv.z);
        r.w = bb.w + dd * (acc.w + dd * sv.w);
        out4[d * 4 + f] = r;
    }
}

extern "C" void kernel_launch(void* const* d_in, const int* in_sizes, int n_in,
                              void* d_out, int out_size, void* d_ws, size_t ws_size,
                              hipStream_t stream) {
    const float* x  = (const float*)d_in[0];          // [50000, 64]
    const int*   ei = (const int*)d_in[1];            // [2, 800000]
    const float* W1 = (const float*)d_in[2];          // [64, 64]
    const float* b1 = (const float*)d_in[3];          // [64]
    const float* W2 = (const float*)d_in[4];          // [64, 16]
    const float* b2 = (const float*)d_in[5];          // [16]
    float* out = (float*)d_out;                       // [50000, 16]

    const int* src = ei;
    const int* dst = ei + N_EDGES;

    // ws layout (4B words), lifetime-overlapped, 27.6 MB total:
    //   dinv       [0, 50048)
    //   node_start [50048, 100352)     (50001 used)
    //   cursor     [100352, 100608)
    //   bsum       [100608, 100864)
    //   csr ushort [100864, 500864)    (800000 ushorts)
    //   h0/h1      [500864, 3700864)   ; nodecnt & pairs alias h0 (both dead before gemm1)
    //   agg1       [3700864, 6900864)
    float*          dinv       = (float*)d_ws;
    int*            node_start = (int*)d_ws + 50048;
    int*            cursor     = (int*)d_ws + 100352;
    int*            bsum       = (int*)d_ws + 100608;
    unsigned short* csr        = (unsigned short*)((int*)d_ws + 100864);
    float*          h0         = (float*)d_ws + 500864;
    float*          agg1       = (float*)d_ws + 3700864;
    int*            nodecnt    = (int*)h0;      // dead after k_scan_local/k_dinv
    unsigned*       pairs      = (unsigned*)h0; // live binscatter..binsort, dead before gemm1
    float*          h1         = h0;            // h0 dead after gather1

    k_zero      <<<(N_NODES + 255) / 256, 256, 0, stream>>>(nodecnt);
    k_count     <<<(N_EDGES + 255) / 256, 256, 0, stream>>>(dst, nodecnt);
    k_dinv      <<<(N_NODES + 255) / 256, 256, 0, stream>>>(nodecnt, dinv);
    k_scan_local<<<SCAN_NB, 256, 0, stream>>>(nodecnt, node_start, bsum);
    k_scan_sums <<<1, 256, 0, stream>>>(bsum);
    k_scan_add  <<<SCAN_NB, 256, 0, stream>>>(node_start, bsum, cursor);
    k_binscatter<<<NSB, 256, 0, stream>>>(src, dst, cursor, pairs);
    k_binsort   <<<NBINS, 256, 0, stream>>>(node_start, pairs, csr);

    k_gemm1   <<<N_NODES / 4, 256, 0, stream>>>(x, W1, h0);
    k_gather1 <<<N_NODES / 4, 256, 0, stream>>>(node_start, csr, dinv, (const float4*)h0,
                                                (float4*)agg1);
    k_gemm2   <<<N_NODES / 16, 256, 0, stream>>>(agg1, b1, W2, h1);
    k_gather2 <<<N_NODES / 4, 256, 0, stream>>>(node_start, csr, dinv, (const float4*)h1,
                                                (const float4*)b2, (float4*)out);
}

// Round 6
// 212.169 us; speedup vs baseline: 3.1389x; 1.1131x over previous
//
#include <hip/hip_runtime.h>

#define N_NODES 50000
#define N_EDGES 800000
#define F1 64
#define F2 16
#define NBINS 196      // ceil(50000/256)
#define BIN_SHIFT 8    // 256 nodes per bin
#define EPB 4096       // edges per binscatter block
#define NSB ((N_EDGES + EPB - 1) / EPB)   // 196
#define SCAN_NB 196
#define STAGE_MAX 6144 // max edges/bin (mean 4082, sigma 64)
#define GEMM1_NB (N_NODES / 4)  // 12500

// ---------------- degree ----------------
__global__ void k_zero(int* __restrict__ cnt) {
    int i = blockIdx.x * blockDim.x + threadIdx.x;
    if (i < N_NODES) cnt[i] = 0;
}

__global__ void k_count(const int* __restrict__ dst, int* __restrict__ cnt) {
    int i = blockIdx.x * blockDim.x + threadIdx.x;
    if (i < N_EDGES) atomicAdd(&cnt[dst[i]], 1);
}

// ---------------- scan step 1 (+dinv fused) ----------------
__global__ void k_scan_local(const int* __restrict__ cnt, float* __restrict__ dinv,
                             int* __restrict__ node_start, int* __restrict__ bsum) {
    __shared__ int tmp[256];
    int t = threadIdx.x;
    int g = blockIdx.x * 256 + t;
    int v = (g < N_NODES) ? cnt[g] : 0;
    if (g < N_NODES) dinv[g] = rsqrtf(1.0f + (float)v);  // +1 self-loop
    tmp[t] = v;
    __syncthreads();
    for (int s = 1; s < 256; s <<= 1) {
        int u = (t >= s) ? tmp[t - s] : 0;
        __syncthreads();
        tmp[t] += u;
        __syncthreads();
    }
    if (g < N_NODES) node_start[g] = tmp[t] - v;  // exclusive
    if (t == 255) bsum[blockIdx.x] = tmp[255];
}

__global__ void k_scan_sums(int* __restrict__ bsum) {
    __shared__ int tmp[256];
    int t = threadIdx.x;
    int v = (t < SCAN_NB) ? bsum[t] : 0;
    tmp[t] = v;
    __syncthreads();
    for (int s = 1; s < 256; s <<= 1) {
        int u = (t >= s) ? tmp[t - s] : 0;
        __syncthreads();
        tmp[t] += u;
        __syncthreads();
    }
    if (t < SCAN_NB) bsum[t] = tmp[t] - v;
}

__global__ void k_scan_add(int* __restrict__ node_start, const int* __restrict__ bsum,
                           int* __restrict__ cursor) {
    int g = blockIdx.x * 256 + threadIdx.x;
    if (g < N_NODES) {
        int v = node_start[g] + bsum[blockIdx.x];
        node_start[g] = v;
        if ((g & 255) == 0) cursor[g >> BIN_SHIFT] = v;  // bin base = node_start[b<<8]
    }
    if (g == 0) node_start[N_NODES] = N_EDGES;
}

// ---------------- fused: binscatter (blocks 0..NSB-1)  ||  gemm1 (blocks NSB..) ----------------
__global__ void __launch_bounds__(256) k_bs_gemm1(
        const int* __restrict__ src, const int* __restrict__ dst,
        int* __restrict__ cursor, unsigned* __restrict__ pairs,
        const float* __restrict__ x, const float* __restrict__ W1,
        float* __restrict__ h0) {
    __shared__ int smem[5136];   // 20.5 KB, shared by both branches
    int t = threadIdx.x;         // 256

    if (blockIdx.x < NSB) {
        // ---- binscatter: coarse-bin edges by dst>>8 with coalesced flushes ----
        int* hist    = smem;            // 196
        int* loff    = smem + 196;
        int* lcur    = smem + 392;
        int* gbase   = smem + 588;
        int* scanbuf = smem + 784;      // 256
        unsigned* stage = (unsigned*)(smem + 1040);  // 4096
        int e0 = blockIdx.x * EPB;
        int eend = min(e0 + EPB, N_EDGES);

        for (int i = t; i < NBINS; i += 256) hist[i] = 0;
        __syncthreads();
        for (int e = e0 + t; e < eend; e += 256)
            atomicAdd(&hist[dst[e] >> BIN_SHIFT], 1);
        __syncthreads();
        int v = (t < NBINS) ? hist[t] : 0;
        scanbuf[t] = v;
        __syncthreads();
        for (int s = 1; s < 256; s <<= 1) {
            int u = (t >= s) ? scanbuf[t - s] : 0;
            __syncthreads();
            scanbuf[t] += u;
            __syncthreads();
        }
        if (t < NBINS) { loff[t] = scanbuf[t] - v; lcur[t] = scanbuf[t] - v; }
        __syncthreads();
        for (int e = e0 + t; e < eend; e += 256) {
            int d = dst[e];
            int b = d >> BIN_SHIFT;
            int pos = atomicAdd(&lcur[b], 1);
            stage[pos] = (unsigned)src[e] | ((unsigned)(d & 255) << 16);  // src < 2^16
        }
        __syncthreads();
        if (t < NBINS) gbase[t] = atomicAdd(&cursor[t], hist[t]);
        __syncthreads();
        int lane = t & 63, wid = t >> 6;
        for (int b = wid; b < NBINS; b += 4) {
            int n = hist[b], lb = loff[b], gb = gbase[b];
            for (int i = lane; i < n; i += 64) pairs[gb + i] = stage[lb + i];
        }
    } else {
        // ---- gemm1: h0 = x @ W1, one wave per row ----
        float* Ws = (float*)smem;         // 4096
        float* Xs = (float*)smem + 4096;  // 256
        int bid = blockIdx.x - NSB;
        int row_local = t >> 6;
        int col = t & 63;
        int row = bid * 4 + row_local;

        for (int i = t; i < F1 * F1; i += 256) Ws[i] = W1[i];
        Xs[t] = x[bid * 4 * F1 + t];
        __syncthreads();

        const float* xr = &Xs[row_local * F1];
        float acc = 0.f;
#pragma unroll
        for (int k = 0; k < F1; ++k) acc += xr[k] * Ws[k * F1 + col];
        h0[row * F1 + col] = acc;
    }
}

// ---------------- per-bin counting sort -> node-sorted ushort CSR ----------------
__global__ void k_binsort(const int* __restrict__ node_start, const unsigned* __restrict__ pairs,
                          unsigned short* __restrict__ csr) {
    __shared__ int hist[256];
    __shared__ int lcur[256];
    __shared__ int scanbuf[256];
    __shared__ unsigned short stage[STAGE_MAX];
    int t = threadIdx.x;                         // 256
    int b = blockIdx.x;
    int lo = b << BIN_SHIFT;
    int hi = min(lo + 256, N_NODES);
    int start = node_start[lo], end = node_start[hi];
    int n = end - start;

    hist[t] = 0;
    __syncthreads();
    for (int i = t; i < n; i += 256)
        atomicAdd(&hist[pairs[start + i] >> 16], 1);
    __syncthreads();
    int v = hist[t];
    scanbuf[t] = v;
    __syncthreads();
    for (int s = 1; s < 256; s <<= 1) {
        int u = (t >= s) ? scanbuf[t - s] : 0;
        __syncthreads();
        scanbuf[t] += u;
        __syncthreads();
    }
    lcur[t] = scanbuf[t] - v;
    __syncthreads();
    for (int i = t; i < n; i += 256) {
        unsigned p = pairs[start + i];
        int pos = atomicAdd(&lcur[p >> 16], 1);
        stage[pos] = (unsigned short)(p & 0xFFFF);
    }
    __syncthreads();
    for (int i = t; i < n; i += 256) csr[start + i] = stage[i];  // coalesced
}

// ---------------- fused layer-1 gather + layer-2 GEMM ----------------
// h1[d] = relu( dd*(dd*h0[d] + sum dinv[s]*h0[s]) + b1 ) @ W2
__global__ void __launch_bounds__(256) k_gather1f(
        const int* __restrict__ node_start, const unsigned short* __restrict__ csr,
        const float* __restrict__ dinv, const float4* __restrict__ h04,
        const float* __restrict__ b1, const float* __restrict__ W2,
        float* __restrict__ h1) {
    __shared__ float W2s[F1 * 17];     // stride 17: breaks 4-way bank conflict
    __shared__ float b1s[F1];
    __shared__ float4 rowbuf[4][16];   // per-wave staged row
    int t = threadIdx.x;               // 256 = 4 waves, one node per wave
    for (int i = t; i < F1 * F2; i += 256) W2s[(i >> 4) * 17 + (i & 15)] = W2[i];
    if (t < F1) b1s[t] = b1[t];
    __syncthreads();

    int lane = t & 63, wid = t >> 6;
    int j = lane >> 4, f = lane & 15;  // 4 edge-groups x float4 slice
    int d = blockIdx.x * 4 + wid;
    int start = node_start[d], end = node_start[d + 1];
    float4 acc = {0.f, 0.f, 0.f, 0.f};
    int i = start + j;
    for (; i + 4 < end; i += 8) {      // 2 chains for MLP
        int s0 = csr[i], s1 = csr[i + 4];
        float w0 = dinv[s0], w1 = dinv[s1];
        float4 v0 = h04[s0 * 16 + f], v1 = h04[s1 * 16 + f];
        acc.x += w0 * v0.x + w1 * v1.x;
        acc.y += w0 * v0.y + w1 * v1.y;
        acc.z += w0 * v0.z + w1 * v1.z;
        acc.w += w0 * v0.w + w1 * v1.w;
    }
    if (i < end) {
        int s = csr[i];
        float w = dinv[s];
        float4 v = h04[s * 16 + f];
        acc.x += w * v.x; acc.y += w * v.y; acc.z += w * v.z; acc.w += w * v.w;
    }
#pragma unroll
    for (int m = 16; m <= 32; m <<= 1) {
        acc.x += __shfl_xor(acc.x, m);
        acc.y += __shfl_xor(acc.y, m);
        acc.z += __shfl_xor(acc.z, m);
        acc.w += __shfl_xor(acc.w, m);
    }
    if (j == 0) {                      // agg + bias + relu, staged for the 64->16 matmul
        float dd = dinv[d];
        float4 sv = h04[d * 16 + f];
        float4 r;
        r.x = fmaxf(dd * (acc.x + dd * sv.x) + b1s[4 * f + 0], 0.f);
        r.y = fmaxf(dd * (acc.y + dd * sv.y) + b1s[4 * f + 1], 0.f);
        r.z = fmaxf(dd * (acc.z + dd * sv.z) + b1s[4 * f + 2], 0.f);
        r.w = fmaxf(dd * (acc.w + dd * sv.w) + b1s[4 * f + 3], 0.f);
        rowbuf[wid][f] = r;
    }
    __syncthreads();                   // LDS visibility (straight-line, all threads reach)

    // matmul 64 -> 16: group g covers k in [16g,16g+16), lane c = output col
    int g = j, c = f;
    const float* row = (const float*)rowbuf[wid];
    float p = 0.f;
#pragma unroll
    for (int kk = 0; kk < 16; ++kk)
        p += row[g * 16 + kk] * W2s[(g * 16 + kk) * 17 + c];
    p += __shfl_xor(p, 16);
    p += __shfl_xor(p, 32);
    if (g == 0) h1[d * F2 + c] = p;
}

// ---------------- layer 2 pull gather (float4, 16 edges/wave/iter) ----------------
__global__ void k_gather2(const int* __restrict__ node_start, const unsigned short* __restrict__ csr,
                          const float* __restrict__ dinv, const float4* __restrict__ h14,
                          const float4* __restrict__ b24, float4* __restrict__ out4) {
    int t = threadIdx.x;                 // 256 = 4 waves, one node per wave
    int lane = t & 63;
    int j = lane >> 2, f = lane & 3;     // 16 edge-groups x 16B slice (F2=16)
    int d = blockIdx.x * 4 + (t >> 6);
    int start = node_start[d], end = node_start[d + 1];
    float4 acc = {0.f, 0.f, 0.f, 0.f};
    for (int i = start + j; i < end; i += 16) {
        int s = csr[i];
        float w = dinv[s];
        float4 v = h14[s * 4 + f];
        acc.x += w * v.x; acc.y += w * v.y; acc.z += w * v.z; acc.w += w * v.w;
    }
#pragma unroll
    for (int m = 4; m <= 32; m <<= 1) {
        acc.x += __shfl_xor(acc.x, m);
        acc.y += __shfl_xor(acc.y, m);
        acc.z += __shfl_xor(acc.z, m);
        acc.w += __shfl_xor(acc.w, m);
    }
    if (j == 0) {
        float dd = dinv[d];
        float4 sv = h14[d * 4 + f];
        float4 bb = b24[f];
        float4 r;
        r.x = bb.x + dd * (acc.x + dd * sv.x);
        r.y = bb.y + dd * (acc.y + dd * sv.y);
        r.z = bb.z + dd * (acc.z + dd * sv.z);
        r.w = bb.w + dd * (acc.w + dd * sv.w);
        out4[d * 4 + f] = r;
    }
}

extern "C" void kernel_launch(void* const* d_in, const int* in_sizes, int n_in,
                              void* d_out, int out_size, void* d_ws, size_t ws_size,
                              hipStream_t stream) {
    const float* x  = (const float*)d_in[0];          // [50000, 64]
    const int*   ei = (const int*)d_in[1];            // [2, 800000]
    const float* W1 = (const float*)d_in[2];          // [64, 64]
    const float* b1 = (const float*)d_in[3];          // [64]
    const float* W2 = (const float*)d_in[4];          // [64, 16]
    const float* b2 = (const float*)d_in[5];          // [16]
    float* out = (float*)d_out;                       // [50000, 16]

    const int* src = ei;
    const int* dst = ei + N_EDGES;

    // ws layout (4B words), no aliasing, 21.4 MB total:
    float*          dinv       = (float*)d_ws;                         // [0, 50048)
    int*            node_start = (int*)d_ws + 50048;                   // 50001 used
    int*            cursor     = (int*)d_ws + 100352;                  // 196
    int*            bsum       = (int*)d_ws + 100608;                  // 196
    unsigned short* csr        = (unsigned short*)((int*)d_ws + 100864);  // 800000 u16
    unsigned*       pairs      = (unsigned*)d_ws + 500864;             // 800000
    float*          h0         = (float*)d_ws + 1300864;               // 3,200,000
    float*          h1         = (float*)d_ws + 4500864;               // 800,000
    int*            nodecnt    = (int*)d_ws + 5300864;                 // 50048

    k_zero      <<<(N_NODES + 255) / 256, 256, 0, stream>>>(nodecnt);
    k_count     <<<(N_EDGES + 255) / 256, 256, 0, stream>>>(dst, nodecnt);
    k_scan_local<<<SCAN_NB, 256, 0, stream>>>(nodecnt, dinv, node_start, bsum);
    k_scan_sums <<<1, 256, 0, stream>>>(bsum);
    k_scan_add  <<<SCAN_NB, 256, 0, stream>>>(node_start, bsum, cursor);
    k_bs_gemm1  <<<NSB + GEMM1_NB, 256, 0, stream>>>(src, dst, cursor, pairs, x, W1, h0);
    k_binsort   <<<NBINS, 256, 0, stream>>>(node_start, pairs, csr);
    k_gather1f  <<<N_NODES / 4, 256, 0, stream>>>(node_start, csr, dinv, (const float4*)h0,
                                                  b1, W2, h1);
    k_gather2   <<<N_NODES / 4, 256, 0, stream>>>(node_start, csr, dinv, (const float4*)h1,
                                                  (const float4*)b2, (float4*)out);
}